// Round 1
// 591.958 us; speedup vs baseline: 1.0360x; 1.0360x over previous
//
#include <hip/hip_runtime.h>
#include <stdint.h>

#define BATCH 16384
#define IN_DIM 1024
#define HDIM 4096

typedef _Float16 f16x8 __attribute__((ext_vector_type(8)));
typedef short short8 __attribute__((ext_vector_type(8)));
typedef float f32x16 __attribute__((ext_vector_type(16)));
typedef int i32x4 __attribute__((ext_vector_type(4)));
typedef int i32x16 __attribute__((ext_vector_type(16)));

typedef const __attribute__((address_space(1))) void* gas_ptr;
typedef __attribute__((address_space(3))) void* las_ptr;

__device__ __forceinline__ void async_copy16(const void* g, void* l) {
  __builtin_amdgcn_global_load_lds((gas_ptr)g, (las_ptr)l, 16, 0, 0);
}

// ---------------- prep kernels (unchanged) ----------------

__global__ void cvt_x_f16_kernel(const float* __restrict__ in,
                                 unsigned short* __restrict__ out, int n4) {
  int i = blockIdx.x * blockDim.x + threadIdx.x;
  if (i < n4) {
    const float4 v = ((const float4*)in)[i];
    ushort4 o;
    o.x = __builtin_bit_cast(unsigned short, (_Float16)v.x);
    o.y = __builtin_bit_cast(unsigned short, (_Float16)v.y);
    o.z = __builtin_bit_cast(unsigned short, (_Float16)v.z);
    o.w = __builtin_bit_cast(unsigned short, (_Float16)v.w);
    ((ushort4*)out)[i] = o;
  }
}

__global__ void cvt_s_kernel(const int* __restrict__ s1, unsigned short* __restrict__ o1, int n1_4,
                             const int* __restrict__ s2, unsigned int* __restrict__ o2, int n2_4) {
  int i = blockIdx.x * blockDim.x + threadIdx.x;
  if (i < n1_4) {
    const int4 v = ((const int4*)s1)[i];
    ushort4 o;
    o.x = __builtin_bit_cast(unsigned short, (_Float16)(float)v.x);
    o.y = __builtin_bit_cast(unsigned short, (_Float16)(float)v.y);
    o.z = __builtin_bit_cast(unsigned short, (_Float16)(float)v.z);
    o.w = __builtin_bit_cast(unsigned short, (_Float16)(float)v.w);
    ((ushort4*)o1)[i] = o;
  } else if (i < n1_4 + n2_4) {
    const int j = i - n1_4;
    const int4 v = ((const int4*)s2)[j];
    o2[j] = (v.x & 0xffu) | ((v.y & 0xffu) << 8) | ((v.z & 0xffu) << 16) | ((v.w & 0xffu) << 24);
  }
}

// scale1 = max(softplus(ls1),1e-4); scale2 = max(softplus(ls2),1e-4)/127
// out[i] = b_out[0] for ALL out_size rows (launch covers max(out_size, 2*HDIM)).
__global__ void scales_init_kernel(const float* __restrict__ ls1, float* __restrict__ s1,
                                   const float* __restrict__ ls2, float* __restrict__ s2,
                                   const float* __restrict__ b_out, float* __restrict__ out,
                                   int out_n) {
  int i = blockIdx.x * blockDim.x + threadIdx.x;
  if (i < out_n) out[i] = b_out[0];
  if (i < HDIM) {
    float l = ls1[i];
    float sp = (l > 20.0f) ? l : log1pf(expf(l));
    s1[i] = fmaxf(sp, 1e-4f);
  } else if (i < 2 * HDIM) {
    float l = ls2[i - HDIM];
    float sp = (l > 20.0f) ? l : log1pf(expf(l));
    s2[i - HDIM] = fmaxf(sp, 1e-4f) * (1.0f / 127.0f);
  }
}

// ---------------- GEMM1 (f16 MFMA, 256x256 tile, 8 waves, 2-phase dbuf) -----
// A: x_f16 [M][1024], B: state1_f16 [4096][1024] (B^T layout).
// BK=64 halfs (128 B rows). LDS: 2 buffers x (A 32KB + B 32KB) = 128 KB (dynamic).
// 8 waves as 2M x 4N; per-wave 128x64 via 4x2 mfma_f32_32x32x16_f16.
// Swizzle: 16B chunk c of row r lives at slot c^(r&7).
// Schedule (T3-min 2-phase): stage(next) issued FIRST, then compute(cur),
// then ONE __syncthreads (implicit vmcnt(0)+lgkmcnt(0) makes this race-free).

__global__ __launch_bounds__(512, 2)
void gemm1_kernel(const unsigned short* __restrict__ A,
                  const unsigned short* __restrict__ B,
                  const float* __restrict__ scale,
                  const float* __restrict__ bias,
                  signed char* __restrict__ Hout) {
  constexpr int K = IN_DIM;
  extern __shared__ __align__(16) char smem[];
  unsigned short* const S = (unsigned short*)smem;  // As[2]: 0,16384  Bs[2]: 32768,49152 (halfs)

  const int tid = threadIdx.x;
  const int wave = tid >> 6;
  const int lane = tid & 63;
  const int r31 = lane & 31;
  const int half = lane >> 5;
  const int wm = wave >> 2;   // 0..1 -> 128 rows each
  const int wn = wave & 3;    // 0..3 -> 64 cols each
  const int row0 = blockIdx.y * 256;
  const int col0 = blockIdx.x * 256;

  f32x16 acc[4][2];
#pragma unroll
  for (int i = 0; i < 4; ++i)
#pragma unroll
    for (int j = 0; j < 2; ++j)
#pragma unroll
      for (int r = 0; r < 16; ++r) acc[i][j][r] = 0.0f;

  const unsigned short* Ab = A + (size_t)row0 * K;
  const unsigned short* Bb = B + (size_t)col0 * K;

  auto stage = [&](int buf, int k0) {
    unsigned short* As = S + buf * 16384;
    unsigned short* Bs = S + 32768 + buf * 16384;
    // A: 256 rows x 128 B = 2048 chunks of 16 B, 4 rounds of 512 threads.
#pragma unroll
    for (int rd = 0; rd < 4; ++rd) {
      const int p = rd * 512 + tid;
      const int r = p >> 3;
      const int c = (p & 7) ^ (r & 7);
      async_copy16(Ab + (size_t)r * K + k0 + c * 8, &As[(rd * 512 + wave * 64) * 8]);
    }
#pragma unroll
    for (int rd = 0; rd < 4; ++rd) {
      const int p = rd * 512 + tid;
      const int r = p >> 3;
      const int c = (p & 7) ^ (r & 7);
      async_copy16(Bb + (size_t)r * K + k0 + c * 8, &Bs[(rd * 512 + wave * 64) * 8]);
    }
  };

  constexpr int NT = K / 64;  // 16
  stage(0, 0);
  __syncthreads();
  int cur = 0;
  for (int t = 0; t < NT; ++t) {
    if (t + 1 < NT) stage(cur ^ 1, (t + 1) * 64);  // issue-early: hides under MFMA
    const unsigned short* As = S + cur * 16384;
    const unsigned short* Bs = S + 32768 + cur * 16384;
    // 4 k-steps of 16: row = lane&31, k = s*16 + half*8 + e -> chunk c = s*2+half
#pragma unroll
    for (int s = 0; s < 4; ++s) {
      const int c = s * 2 + half;
      f16x8 aF[4], bF[2];
#pragma unroll
      for (int i = 0; i < 4; ++i) {
        const int ar = wm * 128 + i * 32 + r31;
        const int cp = c ^ (ar & 7);
        aF[i] = __builtin_bit_cast(f16x8, *(const short8*)&As[ar * 64 + cp * 8]);
      }
#pragma unroll
      for (int j = 0; j < 2; ++j) {
        const int br = wn * 64 + j * 32 + r31;
        const int cp = c ^ (br & 7);
        bF[j] = __builtin_bit_cast(f16x8, *(const short8*)&Bs[br * 64 + cp * 8]);
      }
      __builtin_amdgcn_s_setprio(1);
#pragma unroll
      for (int i = 0; i < 4; ++i)
#pragma unroll
        for (int j = 0; j < 2; ++j)
          acc[i][j] = __builtin_amdgcn_mfma_f32_32x32x16_f16(aF[i], bF[j], acc[i][j], 0, 0, 0);
      __builtin_amdgcn_s_setprio(0);
    }
    __syncthreads();  // drains vmcnt(0): next buffer staged + this buffer's reads done
    cur ^= 1;
  }

  // C/D 32x32 layout: col = lane&31, row = (reg&3)+8*(reg>>2)+4*(lane>>5)
#pragma unroll
  for (int j = 0; j < 2; ++j) {
    const int col = col0 + wn * 64 + j * 32 + r31;
    const float sc = scale[col];
    const float bs = bias[col];
#pragma unroll
    for (int i = 0; i < 4; ++i) {
      const int rbase = row0 + wm * 128 + i * 32 + 4 * half;
#pragma unroll
      for (int r = 0; r < 16; ++r) {
        const int row = rbase + (r & 3) + 8 * (r >> 2);
        float v = fminf(fmaxf(acc[i][j][r] * sc + bs, -1.0f), 1.0f);
        Hout[(size_t)row * HDIM + col] = (signed char)(int)rintf(v * 127.0f);
      }
    }
  }
}

// ---------------- GEMM2 (i8 MFMA, 256x256 tile, 8 waves, 2-phase dbuf) ------
// A: h1_i8 [M][4096], B: state2_i8 [4096][4096] (exact ternary).
// BK=128 bytes. LDS layout/schedule identical byte-structure to gemm1.
// mfma_i32_32x32x32_i8, exact i32 accumulation; fused OUT_DIM=1 head epilogue.

__global__ __launch_bounds__(512, 2)
void gemm2_kernel(const signed char* __restrict__ A,
                  const signed char* __restrict__ B,
                  const float* __restrict__ scale,   // softplus/127
                  const float* __restrict__ bias,
                  const float* __restrict__ w_out,
                  float* __restrict__ out) {
  constexpr int K = HDIM;
  extern __shared__ __align__(16) char smem[];
  signed char* const S = (signed char*)smem;  // As[2]: 0,32768  Bs[2]: 65536,98304 (bytes)

  const int tid = threadIdx.x;
  const int wave = tid >> 6;
  const int lane = tid & 63;
  const int r31 = lane & 31;
  const int half = lane >> 5;
  const int wm = wave >> 2;
  const int wn = wave & 3;
  const int row0 = blockIdx.y * 256;
  const int col0 = blockIdx.x * 256;

  i32x16 acc[4][2];
#pragma unroll
  for (int i = 0; i < 4; ++i)
#pragma unroll
    for (int j = 0; j < 2; ++j)
#pragma unroll
      for (int r = 0; r < 16; ++r) acc[i][j][r] = 0;

  const signed char* Ab = A + (size_t)row0 * K;
  const signed char* Bb = B + (size_t)col0 * K;

  auto stage = [&](int buf, int k0) {
    signed char* As = S + buf * 32768;
    signed char* Bs = S + 65536 + buf * 32768;
#pragma unroll
    for (int rd = 0; rd < 4; ++rd) {
      const int p = rd * 512 + tid;
      const int r = p >> 3;
      const int c = (p & 7) ^ (r & 7);
      async_copy16(Ab + (size_t)r * K + k0 + c * 16, &As[(rd * 512 + wave * 64) * 16]);
    }
#pragma unroll
    for (int rd = 0; rd < 4; ++rd) {
      const int p = rd * 512 + tid;
      const int r = p >> 3;
      const int c = (p & 7) ^ (r & 7);
      async_copy16(Bb + (size_t)r * K + k0 + c * 16, &Bs[(rd * 512 + wave * 64) * 16]);
    }
  };

  constexpr int NT = K / 128;  // 32
  stage(0, 0);
  __syncthreads();
  int cur = 0;
  for (int t = 0; t < NT; ++t) {
    if (t + 1 < NT) stage(cur ^ 1, (t + 1) * 128);
    const signed char* As = S + cur * 32768;
    const signed char* Bs = S + 65536 + cur * 32768;
    // 4 k-steps of 32: row = lane&31, k = s*32 + half*16 + e -> chunk c = s*2+half
#pragma unroll
    for (int s = 0; s < 4; ++s) {
      const int c = s * 2 + half;
      i32x4 aF[4], bF[2];
#pragma unroll
      for (int i = 0; i < 4; ++i) {
        const int ar = wm * 128 + i * 32 + r31;
        const int cp = c ^ (ar & 7);
        aF[i] = *(const i32x4*)&As[ar * 128 + cp * 16];
      }
#pragma unroll
      for (int j = 0; j < 2; ++j) {
        const int br = wn * 64 + j * 32 + r31;
        const int cp = c ^ (br & 7);
        bF[j] = *(const i32x4*)&Bs[br * 128 + cp * 16];
      }
      __builtin_amdgcn_s_setprio(1);
#pragma unroll
      for (int i = 0; i < 4; ++i)
#pragma unroll
        for (int j = 0; j < 2; ++j)
          acc[i][j] = __builtin_amdgcn_mfma_i32_32x32x32_i8(aF[i], bF[j], acc[i][j], 0, 0, 0);
      __builtin_amdgcn_s_setprio(0);
    }
    __syncthreads();
    cur ^= 1;
  }

  // Fused head: out[row] += sum_col clip(acc*sc+bs)*w_out[col]
#pragma unroll
  for (int i = 0; i < 4; ++i) {
    float rs[16];
#pragma unroll
    for (int r = 0; r < 16; ++r) rs[r] = 0.0f;
#pragma unroll
    for (int j = 0; j < 2; ++j) {
      const int col = col0 + wn * 64 + j * 32 + r31;
      const float sc = scale[col];
      const float bs = bias[col];
      const float w = w_out[col];
#pragma unroll
      for (int r = 0; r < 16; ++r) {
        float v = fminf(fmaxf((float)acc[i][j][r] * sc + bs, -1.0f), 1.0f);
        rs[r] += v * w;
      }
    }
#pragma unroll
    for (int off = 1; off < 32; off <<= 1)
#pragma unroll
      for (int r = 0; r < 16; ++r)
        rs[r] += __shfl_xor(rs[r], off, 64);
    if (r31 == 0) {
      const int rbase = row0 + wm * 128 + i * 32 + 4 * half;
#pragma unroll
      for (int r = 0; r < 16; ++r)
        atomicAdd(&out[rbase + (r & 3) + 8 * (r >> 2)], rs[r]);
    }
  }
}

// ---------------- launch ----------------

extern "C" void kernel_launch(void* const* d_in, const int* in_sizes, int n_in,
                              void* d_out, int out_size, void* d_ws, size_t ws_size,
                              hipStream_t stream) {
  (void)in_sizes; (void)n_in; (void)ws_size;
  const float* x          = (const float*)d_in[0];
  const int*   state1     = (const int*)d_in[1];
  const float* log_scale1 = (const float*)d_in[2];
  const float* bias1      = (const float*)d_in[3];
  const int*   state2     = (const int*)d_in[4];
  const float* log_scale2 = (const float*)d_in[5];
  const float* bias2      = (const float*)d_in[6];
  const float* w_out      = (const float*)d_in[7];
  const float* b_out      = (const float*)d_in[8];
  float* out = (float*)d_out;

  // One-time: both GEMMs need 128 KB dynamic LDS (> default 64 KB cap).
  static int lds_attr_done = 0;
  if (!lds_attr_done) {
    hipFuncSetAttribute((const void*)gemm1_kernel,
                        hipFuncAttributeMaxDynamicSharedMemorySize, 131072);
    hipFuncSetAttribute((const void*)gemm2_kernel,
                        hipFuncAttributeMaxDynamicSharedMemorySize, 131072);
    lds_attr_done = 1;
  }

  char* ws = (char*)d_ws;
  unsigned short* xh  = (unsigned short*)ws; ws += (size_t)BATCH * IN_DIM * 2;  // 32 MB
  unsigned short* s1h = (unsigned short*)ws; ws += (size_t)HDIM * IN_DIM * 2;   // 8 MB
  signed char*    s2q = (signed char*)ws;    ws += (size_t)HDIM * HDIM;         // 16 MB
  signed char*    h1q = (signed char*)ws;    ws += (size_t)BATCH * HDIM;        // 64 MB
  float* scale1 = (float*)ws; ws += HDIM * sizeof(float);
  float* scale2 = (float*)ws; ws += HDIM * sizeof(float);

  const int nx4 = BATCH * IN_DIM / 4;
  const int n1_4 = HDIM * IN_DIM / 4;
  const int n2_4 = HDIM * HDIM / 4;

  cvt_x_f16_kernel<<<(nx4 + 255) / 256, 256, 0, stream>>>(x, xh, nx4);
  cvt_s_kernel<<<(n1_4 + n2_4 + 255) / 256, 256, 0, stream>>>(
      state1, s1h, n1_4, state2, (unsigned int*)s2q, n2_4);
  const int init_n = (out_size > 2 * HDIM) ? out_size : 2 * HDIM;
  scales_init_kernel<<<(init_n + 255) / 256, 256, 0, stream>>>(
      log_scale1, scale1, log_scale2, scale2, b_out, out, out_size);

  dim3 grid(HDIM / 256, BATCH / 256);  // 16 x 64
  gemm1_kernel<<<grid, 512, 131072, stream>>>(xh, s1h, scale1, bias1, h1q);
  gemm2_kernel<<<grid, 512, 131072, stream>>>(h1q, s2q, scale2, bias2, w_out, out);
}

// Round 2
// 588.229 us; speedup vs baseline: 1.0426x; 1.0063x over previous
//
#include <hip/hip_runtime.h>
#include <stdint.h>

#define BATCH 16384
#define IN_DIM 1024
#define HDIM 4096

typedef _Float16 f16x8 __attribute__((ext_vector_type(8)));
typedef short short8 __attribute__((ext_vector_type(8)));
typedef float f32x16 __attribute__((ext_vector_type(16)));
typedef int i32x4 __attribute__((ext_vector_type(4)));
typedef int i32x16 __attribute__((ext_vector_type(16)));

typedef const __attribute__((address_space(1))) void* gas_ptr;
typedef __attribute__((address_space(3))) void* las_ptr;

__device__ __forceinline__ void async_copy16(const void* g, void* l) {
  __builtin_amdgcn_global_load_lds((gas_ptr)g, (las_ptr)l, 16, 0, 0);
}

// Compiler fence + raw barrier (NOT __syncthreads: that emits vmcnt(0) every
// phase and drains the staging pipeline -- the m218 drain0 anti-pattern).
#define FENCE asm volatile("" ::: "memory")
#define BARRIER do { FENCE; __builtin_amdgcn_s_barrier(); FENCE; } while (0)

// ---------------- prep kernels (unchanged) ----------------

__global__ void cvt_x_f16_kernel(const float* __restrict__ in,
                                 unsigned short* __restrict__ out, int n4) {
  int i = blockIdx.x * blockDim.x + threadIdx.x;
  if (i < n4) {
    const float4 v = ((const float4*)in)[i];
    ushort4 o;
    o.x = __builtin_bit_cast(unsigned short, (_Float16)v.x);
    o.y = __builtin_bit_cast(unsigned short, (_Float16)v.y);
    o.z = __builtin_bit_cast(unsigned short, (_Float16)v.z);
    o.w = __builtin_bit_cast(unsigned short, (_Float16)v.w);
    ((ushort4*)out)[i] = o;
  }
}

__global__ void cvt_s_kernel(const int* __restrict__ s1, unsigned short* __restrict__ o1, int n1_4,
                             const int* __restrict__ s2, unsigned int* __restrict__ o2, int n2_4) {
  int i = blockIdx.x * blockDim.x + threadIdx.x;
  if (i < n1_4) {
    const int4 v = ((const int4*)s1)[i];
    ushort4 o;
    o.x = __builtin_bit_cast(unsigned short, (_Float16)(float)v.x);
    o.y = __builtin_bit_cast(unsigned short, (_Float16)(float)v.y);
    o.z = __builtin_bit_cast(unsigned short, (_Float16)(float)v.z);
    o.w = __builtin_bit_cast(unsigned short, (_Float16)(float)v.w);
    ((ushort4*)o1)[i] = o;
  } else if (i < n1_4 + n2_4) {
    const int j = i - n1_4;
    const int4 v = ((const int4*)s2)[j];
    o2[j] = (v.x & 0xffu) | ((v.y & 0xffu) << 8) | ((v.z & 0xffu) << 16) | ((v.w & 0xffu) << 24);
  }
}

// scale1 = max(softplus(ls1),1e-4); scale2 = max(softplus(ls2),1e-4)/127
// out[i] = b_out[0] for ALL out_size rows (launch covers max(out_size, 2*HDIM)).
__global__ void scales_init_kernel(const float* __restrict__ ls1, float* __restrict__ s1,
                                   const float* __restrict__ ls2, float* __restrict__ s2,
                                   const float* __restrict__ b_out, float* __restrict__ out,
                                   int out_n) {
  int i = blockIdx.x * blockDim.x + threadIdx.x;
  if (i < out_n) out[i] = b_out[0];
  if (i < HDIM) {
    float l = ls1[i];
    float sp = (l > 20.0f) ? l : log1pf(expf(l));
    s1[i] = fmaxf(sp, 1e-4f);
  } else if (i < 2 * HDIM) {
    float l = ls2[i - HDIM];
    float sp = (l > 20.0f) ? l : log1pf(expf(l));
    s2[i - HDIM] = fmaxf(sp, 1e-4f) * (1.0f / 127.0f);
  }
}

// ---------------- GEMM1 (f16 MFMA, 256x256, 8 waves, 8-phase-style) --------
// A: x_f16 [M][1024], B: state1_f16 [4096][1024] (B^T layout). BK=64 halfs.
// LDS: 2 x (A 32KB + B 32KB) = 128 KB. Waves 2M x 4N, per-wave 128x64.
// Per K-tile: 4 phases, each {6 ds_read_b128 | 2-3 stage loads for t+1 |
// s_barrier | setprio(1) 8xMFMA setprio(0) | s_barrier}. Staging only in
// phases 0-2; single counted drain (vmcnt(0) after phase-3 MFMAs) per tile.
// Safety: stage always writes the opposite buffer; end-of-tile barrier
// separates read/write epochs (each wave's reads are consumed by its MFMAs
// before it reaches the barrier).

__global__ __launch_bounds__(512, 2)
void gemm1_kernel(const unsigned short* __restrict__ A,
                  const unsigned short* __restrict__ B,
                  const float* __restrict__ scale,
                  const float* __restrict__ bias,
                  signed char* __restrict__ Hout) {
  constexpr int K = IN_DIM;
  extern __shared__ __align__(16) char smem[];
  unsigned short* const S = (unsigned short*)smem;  // As[2]: 0,16384  Bs[2]: 32768,49152 (halfs)

  const int tid = threadIdx.x;
  const int wave = tid >> 6;
  const int lane = tid & 63;
  const int r31 = lane & 31;
  const int half = lane >> 5;
  const int wm = wave >> 2;
  const int wn = wave & 3;
  const int row0 = blockIdx.y * 256;
  const int col0 = blockIdx.x * 256;

  f32x16 acc[4][2];
#pragma unroll
  for (int i = 0; i < 4; ++i)
#pragma unroll
    for (int j = 0; j < 2; ++j)
#pragma unroll
      for (int r = 0; r < 16; ++r) acc[i][j][r] = 0.0f;

  const unsigned short* Ab = A + (size_t)row0 * K;
  const unsigned short* Bb = B + (size_t)col0 * K;

// stage round rd (0..3) of A or B for k-offset nk0 into buffers An/Bn.
// 512 thr x 16 B per round; LDS slot: chunk c of row r at slot c^(r&7).
#define G1_STA(rd)                                                        \
  { const int p = (rd) * 512 + tid; const int r = p >> 3;                 \
    const int cc = (p & 7) ^ (r & 7);                                     \
    async_copy16(Ab + (size_t)r * K + nk0 + cc * 8,                       \
                 &An[((rd) * 512 + wave * 64) * 8]); }
#define G1_STB(rd)                                                        \
  { const int p = (rd) * 512 + tid; const int r = p >> 3;                 \
    const int cc = (p & 7) ^ (r & 7);                                     \
    async_copy16(Bb + (size_t)r * K + nk0 + cc * 8,                       \
                 &Bn[((rd) * 512 + wave * 64) * 8]); }

// phase: ds-load k-step S_, stage, barrier, MFMA cluster. (2nd barrier outside)
#define G1_PHASE(S_, STAGE)                                               \
  {                                                                       \
    const int c = (S_) * 2 + half;                                        \
    f16x8 aF[4], bF[2];                                                   \
    _Pragma("unroll") for (int i = 0; i < 4; ++i) {                       \
      const int ar = wm * 128 + i * 32 + r31;                             \
      const int cp = c ^ (ar & 7);                                        \
      aF[i] = __builtin_bit_cast(f16x8, *(const short8*)&As[ar * 64 + cp * 8]); \
    }                                                                     \
    _Pragma("unroll") for (int j = 0; j < 2; ++j) {                       \
      const int br = wn * 64 + j * 32 + r31;                              \
      const int cp = c ^ (br & 7);                                        \
      bF[j] = __builtin_bit_cast(f16x8, *(const short8*)&Bs[br * 64 + cp * 8]); \
    }                                                                     \
    STAGE;                                                                \
    BARRIER;                                                              \
    __builtin_amdgcn_s_setprio(1);                                        \
    _Pragma("unroll") for (int i = 0; i < 4; ++i)                         \
      _Pragma("unroll") for (int j = 0; j < 2; ++j)                       \
        acc[i][j] = __builtin_amdgcn_mfma_f32_32x32x16_f16(aF[i], bF[j], acc[i][j], 0, 0, 0); \
    __builtin_amdgcn_s_setprio(0);                                        \
  }

  constexpr int NT = K / 64;  // 16
  // Prologue: stage tile 0 into buffer 0, drain, barrier.
  {
    unsigned short* An = S;
    unsigned short* Bn = S + 32768;
    const int nk0 = 0;
    G1_STA(0) G1_STA(1) G1_STA(2) G1_STA(3)
    G1_STB(0) G1_STB(1) G1_STB(2) G1_STB(3)
    asm volatile("s_waitcnt vmcnt(0)" ::: "memory");
    BARRIER;
  }

  for (int t = 0; t < NT; ++t) {
    const unsigned short* As = S + (t & 1) * 16384;
    const unsigned short* Bs = S + 32768 + (t & 1) * 16384;
    unsigned short* An = S + ((t + 1) & 1) * 16384;
    unsigned short* Bn = S + 32768 + ((t + 1) & 1) * 16384;
    const int nk0 = (t + 1) * 64;
    const bool pf = (t + 1 < NT);

    G1_PHASE(0, if (pf) { G1_STA(0) G1_STA(1) G1_STA(2) })
    BARRIER;
    G1_PHASE(1, if (pf) { G1_STA(3) G1_STB(0) G1_STB(1) })
    BARRIER;
    G1_PHASE(2, if (pf) { G1_STB(2) G1_STB(3) })
    BARRIER;
    G1_PHASE(3, )
    asm volatile("s_waitcnt vmcnt(0)" ::: "memory");
    BARRIER;
  }
#undef G1_STA
#undef G1_STB
#undef G1_PHASE

  // C/D 32x32 layout: col = lane&31, row = (reg&3)+8*(reg>>2)+4*(lane>>5)
#pragma unroll
  for (int j = 0; j < 2; ++j) {
    const int col = col0 + wn * 64 + j * 32 + r31;
    const float sc = scale[col];
    const float bs = bias[col];
#pragma unroll
    for (int i = 0; i < 4; ++i) {
      const int rbase = row0 + wm * 128 + i * 32 + 4 * half;
#pragma unroll
      for (int r = 0; r < 16; ++r) {
        const int row = rbase + (r & 3) + 8 * (r >> 2);
        float v = fminf(fmaxf(acc[i][j][r] * sc + bs, -1.0f), 1.0f);
        Hout[(size_t)row * HDIM + col] = (signed char)(int)rintf(v * 127.0f);
      }
    }
  }
}

// ---------------- GEMM2 (i8 MFMA, 256x256, 8 waves, 8-phase-style) ---------
// A: h1_i8 [M][4096], B: state2_i8 [4096][4096] (exact ternary). BK=128 B.
// Same byte-structure/schedule as gemm1; mfma_i32_32x32x32_i8 exact i32
// accumulation; fused OUT_DIM=1 head epilogue.

__global__ __launch_bounds__(512, 2)
void gemm2_kernel(const signed char* __restrict__ A,
                  const signed char* __restrict__ B,
                  const float* __restrict__ scale,   // softplus/127
                  const float* __restrict__ bias,
                  const float* __restrict__ w_out,
                  float* __restrict__ out) {
  constexpr int K = HDIM;
  extern __shared__ __align__(16) char smem[];
  signed char* const S = (signed char*)smem;  // As[2]: 0,32768  Bs[2]: 65536,98304 (bytes)

  const int tid = threadIdx.x;
  const int wave = tid >> 6;
  const int lane = tid & 63;
  const int r31 = lane & 31;
  const int half = lane >> 5;
  const int wm = wave >> 2;
  const int wn = wave & 3;
  const int row0 = blockIdx.y * 256;
  const int col0 = blockIdx.x * 256;

  i32x16 acc[4][2];
#pragma unroll
  for (int i = 0; i < 4; ++i)
#pragma unroll
    for (int j = 0; j < 2; ++j)
#pragma unroll
      for (int r = 0; r < 16; ++r) acc[i][j][r] = 0;

  const signed char* Ab = A + (size_t)row0 * K;
  const signed char* Bb = B + (size_t)col0 * K;

#define G2_STA(rd)                                                        \
  { const int p = (rd) * 512 + tid; const int r = p >> 3;                 \
    const int cc = (p & 7) ^ (r & 7);                                     \
    async_copy16(Ab + (size_t)r * K + nk0 + cc * 16,                      \
                 &An[((rd) * 512 + wave * 64) * 16]); }
#define G2_STB(rd)                                                        \
  { const int p = (rd) * 512 + tid; const int r = p >> 3;                 \
    const int cc = (p & 7) ^ (r & 7);                                     \
    async_copy16(Bb + (size_t)r * K + nk0 + cc * 16,                      \
                 &Bn[((rd) * 512 + wave * 64) * 16]); }

#define G2_PHASE(S_, STAGE)                                               \
  {                                                                       \
    const int c = (S_) * 2 + half;                                        \
    i32x4 aF[4], bF[2];                                                   \
    _Pragma("unroll") for (int i = 0; i < 4; ++i) {                       \
      const int ar = wm * 128 + i * 32 + r31;                             \
      const int cp = c ^ (ar & 7);                                        \
      aF[i] = *(const i32x4*)&As[ar * 128 + cp * 16];                     \
    }                                                                     \
    _Pragma("unroll") for (int j = 0; j < 2; ++j) {                       \
      const int br = wn * 64 + j * 32 + r31;                              \
      const int cp = c ^ (br & 7);                                        \
      bF[j] = *(const i32x4*)&Bs[br * 128 + cp * 16];                     \
    }                                                                     \
    STAGE;                                                                \
    BARRIER;                                                              \
    __builtin_amdgcn_s_setprio(1);                                        \
    _Pragma("unroll") for (int i = 0; i < 4; ++i)                         \
      _Pragma("unroll") for (int j = 0; j < 2; ++j)                       \
        acc[i][j] = __builtin_amdgcn_mfma_i32_32x32x32_i8(aF[i], bF[j], acc[i][j], 0, 0, 0); \
    __builtin_amdgcn_s_setprio(0);                                        \
  }

  constexpr int NT = K / 128;  // 32
  {
    signed char* An = S;
    signed char* Bn = S + 65536;
    const int nk0 = 0;
    G2_STA(0) G2_STA(1) G2_STA(2) G2_STA(3)
    G2_STB(0) G2_STB(1) G2_STB(2) G2_STB(3)
    asm volatile("s_waitcnt vmcnt(0)" ::: "memory");
    BARRIER;
  }

  for (int t = 0; t < NT; ++t) {
    const signed char* As = S + (t & 1) * 32768;
    const signed char* Bs = S + 65536 + (t & 1) * 32768;
    signed char* An = S + ((t + 1) & 1) * 32768;
    signed char* Bn = S + 65536 + ((t + 1) & 1) * 32768;
    const int nk0 = (t + 1) * 128;
    const bool pf = (t + 1 < NT);

    G2_PHASE(0, if (pf) { G2_STA(0) G2_STA(1) G2_STA(2) })
    BARRIER;
    G2_PHASE(1, if (pf) { G2_STA(3) G2_STB(0) G2_STB(1) })
    BARRIER;
    G2_PHASE(2, if (pf) { G2_STB(2) G2_STB(3) })
    BARRIER;
    G2_PHASE(3, )
    asm volatile("s_waitcnt vmcnt(0)" ::: "memory");
    BARRIER;
  }
#undef G2_STA
#undef G2_STB
#undef G2_PHASE

  // Fused head: out[row] += sum_col clip(acc*sc+bs)*w_out[col]
#pragma unroll
  for (int i = 0; i < 4; ++i) {
    float rs[16];
#pragma unroll
    for (int r = 0; r < 16; ++r) rs[r] = 0.0f;
#pragma unroll
    for (int j = 0; j < 2; ++j) {
      const int col = col0 + wn * 64 + j * 32 + r31;
      const float sc = scale[col];
      const float bs = bias[col];
      const float w = w_out[col];
#pragma unroll
      for (int r = 0; r < 16; ++r) {
        float v = fminf(fmaxf((float)acc[i][j][r] * sc + bs, -1.0f), 1.0f);
        rs[r] += v * w;
      }
    }
#pragma unroll
    for (int off = 1; off < 32; off <<= 1)
#pragma unroll
      for (int r = 0; r < 16; ++r)
        rs[r] += __shfl_xor(rs[r], off, 64);
    if (r31 == 0) {
      const int rbase = row0 + wm * 128 + i * 32 + 4 * half;
#pragma unroll
      for (int r = 0; r < 16; ++r)
        atomicAdd(&out[rbase + (r & 3) + 8 * (r >> 2)], rs[r]);
    }
  }
}

// ---------------- launch ----------------

extern "C" void kernel_launch(void* const* d_in, const int* in_sizes, int n_in,
                              void* d_out, int out_size, void* d_ws, size_t ws_size,
                              hipStream_t stream) {
  (void)in_sizes; (void)n_in; (void)ws_size;
  const float* x          = (const float*)d_in[0];
  const int*   state1     = (const int*)d_in[1];
  const float* log_scale1 = (const float*)d_in[2];
  const float* bias1      = (const float*)d_in[3];
  const int*   state2     = (const int*)d_in[4];
  const float* log_scale2 = (const float*)d_in[5];
  const float* bias2      = (const float*)d_in[6];
  const float* w_out      = (const float*)d_in[7];
  const float* b_out      = (const float*)d_in[8];
  float* out = (float*)d_out;

  // One-time: both GEMMs need 128 KB dynamic LDS (> default 64 KB cap).
  static int lds_attr_done = 0;
  if (!lds_attr_done) {
    hipFuncSetAttribute((const void*)gemm1_kernel,
                        hipFuncAttributeMaxDynamicSharedMemorySize, 131072);
    hipFuncSetAttribute((const void*)gemm2_kernel,
                        hipFuncAttributeMaxDynamicSharedMemorySize, 131072);
    lds_attr_done = 1;
  }

  char* ws = (char*)d_ws;
  unsigned short* xh  = (unsigned short*)ws; ws += (size_t)BATCH * IN_DIM * 2;  // 32 MB
  unsigned short* s1h = (unsigned short*)ws; ws += (size_t)HDIM * IN_DIM * 2;   // 8 MB
  signed char*    s2q = (signed char*)ws;    ws += (size_t)HDIM * HDIM;         // 16 MB
  signed char*    h1q = (signed char*)ws;    ws += (size_t)BATCH * HDIM;        // 64 MB
  float* scale1 = (float*)ws; ws += HDIM * sizeof(float);
  float* scale2 = (float*)ws; ws += HDIM * sizeof(float);

  const int nx4 = BATCH * IN_DIM / 4;
  const int n1_4 = HDIM * IN_DIM / 4;
  const int n2_4 = HDIM * HDIM / 4;

  cvt_x_f16_kernel<<<(nx4 + 255) / 256, 256, 0, stream>>>(x, xh, nx4);
  cvt_s_kernel<<<(n1_4 + n2_4 + 255) / 256, 256, 0, stream>>>(
      state1, s1h, n1_4, state2, (unsigned int*)s2q, n2_4);
  const int init_n = (out_size > 2 * HDIM) ? out_size : 2 * HDIM;
  scales_init_kernel<<<(init_n + 255) / 256, 256, 0, stream>>>(
      log_scale1, scale1, log_scale2, scale2, b_out, out, out_size);

  dim3 grid(HDIM / 256, BATCH / 256);  // 16 x 64
  gemm1_kernel<<<grid, 512, 131072, stream>>>(xh, s1h, scale1, bias1, h1q);
  gemm2_kernel<<<grid, 512, 131072, stream>>>(h1q, s2q, scale2, bias2, w_out, out);
}

// Round 3
// 550.569 us; speedup vs baseline: 1.1139x; 1.0684x over previous
//
#include <hip/hip_runtime.h>
#include <stdint.h>

#define BATCH 16384
#define IN_DIM 1024
#define HDIM 4096

typedef _Float16 f16x8 __attribute__((ext_vector_type(8)));
typedef short short8 __attribute__((ext_vector_type(8)));
typedef float f32x16 __attribute__((ext_vector_type(16)));
typedef int i32x4 __attribute__((ext_vector_type(4)));
typedef int i32x16 __attribute__((ext_vector_type(16)));

typedef const __attribute__((address_space(1))) void* gas_ptr;
typedef __attribute__((address_space(3))) void* las_ptr;

__device__ __forceinline__ void async_copy16(const void* g, void* l) {
  __builtin_amdgcn_global_load_lds((gas_ptr)g, (las_ptr)l, 16, 0, 0);
}

#define FENCE asm volatile("" ::: "memory")
#define BARRIER do { FENCE; __builtin_amdgcn_s_barrier(); FENCE; } while (0)

// ---------------- prep kernels (unchanged) ----------------

__global__ void cvt_x_f16_kernel(const float* __restrict__ in,
                                 unsigned short* __restrict__ out, int n4) {
  int i = blockIdx.x * blockDim.x + threadIdx.x;
  if (i < n4) {
    const float4 v = ((const float4*)in)[i];
    ushort4 o;
    o.x = __builtin_bit_cast(unsigned short, (_Float16)v.x);
    o.y = __builtin_bit_cast(unsigned short, (_Float16)v.y);
    o.z = __builtin_bit_cast(unsigned short, (_Float16)v.z);
    o.w = __builtin_bit_cast(unsigned short, (_Float16)v.w);
    ((ushort4*)out)[i] = o;
  }
}

__global__ void cvt_s_kernel(const int* __restrict__ s1, unsigned short* __restrict__ o1, int n1_4,
                             const int* __restrict__ s2, unsigned int* __restrict__ o2, int n2_4) {
  int i = blockIdx.x * blockDim.x + threadIdx.x;
  if (i < n1_4) {
    const int4 v = ((const int4*)s1)[i];
    ushort4 o;
    o.x = __builtin_bit_cast(unsigned short, (_Float16)(float)v.x);
    o.y = __builtin_bit_cast(unsigned short, (_Float16)(float)v.y);
    o.z = __builtin_bit_cast(unsigned short, (_Float16)(float)v.z);
    o.w = __builtin_bit_cast(unsigned short, (_Float16)(float)v.w);
    ((ushort4*)o1)[i] = o;
  } else if (i < n1_4 + n2_4) {
    const int j = i - n1_4;
    const int4 v = ((const int4*)s2)[j];
    o2[j] = (v.x & 0xffu) | ((v.y & 0xffu) << 8) | ((v.z & 0xffu) << 16) | ((v.w & 0xffu) << 24);
  }
}

// scale1 = max(softplus(ls1),1e-4); scale2 = max(softplus(ls2),1e-4)/127
// out[i] = b_out[0] for ALL out_size rows (launch covers max(out_size, 2*HDIM)).
__global__ void scales_init_kernel(const float* __restrict__ ls1, float* __restrict__ s1,
                                   const float* __restrict__ ls2, float* __restrict__ s2,
                                   const float* __restrict__ b_out, float* __restrict__ out,
                                   int out_n) {
  int i = blockIdx.x * blockDim.x + threadIdx.x;
  if (i < out_n) out[i] = b_out[0];
  if (i < HDIM) {
    float l = ls1[i];
    float sp = (l > 20.0f) ? l : log1pf(expf(l));
    s1[i] = fmaxf(sp, 1e-4f);
  } else if (i < 2 * HDIM) {
    float l = ls2[i - HDIM];
    float sp = (l > 20.0f) ? l : log1pf(expf(l));
    s2[i - HDIM] = fmaxf(sp, 1e-4f) * (1.0f / 127.0f);
  }
}

// ---------------- GEMM1 (f16 MFMA, 256x256 tile, 4 waves @ 128x128) --------
// A: x_f16 [M][1024], B: state1_f16 [4096][1024] (B^T). BK=64 halfs.
// GEOMETRY CHANGE (r3): 4 waves 2x2, per-wave 128x128 (acc[4][4]) instead of
// 8 waves @ 128x64. Halves LDS-read redundancy: reads/K-tile/CU 192->128 KB,
// which was the binding pipe (r2 accounting: LDS 3850 cyc vs MFMA 2330).
// 1 wave/SIMD; latency hidden by register-dbuf of fragments (k-step s+1
// loads issued before k-step s MFMAs, all statically indexed).
// LDS: 2 x (A 32KB + B 32KB) = 128 KB. Swizzle unchanged: chunk c of row r
// at slot c^(r&7) (measured at the wave64-b128 bank-pass floor).
// Schedule: stage(t+1) issued at tile top; ONE vmcnt(0)+barrier per tile.

__global__ __launch_bounds__(256, 1)
void gemm1_kernel(const unsigned short* __restrict__ A,
                  const unsigned short* __restrict__ B,
                  const float* __restrict__ scale,
                  const float* __restrict__ bias,
                  signed char* __restrict__ Hout) {
  constexpr int K = IN_DIM;
  extern __shared__ __align__(16) char smem[];
  unsigned short* const S = (unsigned short*)smem;  // As[2]: 0,16384  Bs[2]: 32768,49152 (halfs)

  const int tid = threadIdx.x;
  const int wave = tid >> 6;
  const int lane = tid & 63;
  const int r31 = lane & 31;
  const int half = lane >> 5;
  const int wm = wave >> 1;   // 0..1 -> 128 rows
  const int wn = wave & 1;    // 0..1 -> 128 cols
  const int row0 = blockIdx.y * 256;
  const int col0 = blockIdx.x * 256;

  f32x16 acc[4][4];
#pragma unroll
  for (int i = 0; i < 4; ++i)
#pragma unroll
    for (int j = 0; j < 4; ++j)
#pragma unroll
      for (int r = 0; r < 16; ++r) acc[i][j][r] = 0.0f;

  const unsigned short* Ab = A + (size_t)row0 * K;
  const unsigned short* Bb = B + (size_t)col0 * K;

  auto stage = [&](int buf, int k0) {
    unsigned short* As = S + buf * 16384;
    unsigned short* Bs = S + 32768 + buf * 16384;
    // 256 rows x 128 B = 2048 chunks of 16 B; 8 rounds of 256 threads.
#pragma unroll
    for (int rd = 0; rd < 8; ++rd) {
      const int p = rd * 256 + tid;
      const int r = p >> 3;
      const int c = (p & 7) ^ (r & 7);
      async_copy16(Ab + (size_t)r * K + k0 + c * 8, &As[(rd * 256 + wave * 64) * 8]);
    }
#pragma unroll
    for (int rd = 0; rd < 8; ++rd) {
      const int p = rd * 256 + tid;
      const int r = p >> 3;
      const int c = (p & 7) ^ (r & 7);
      async_copy16(Bb + (size_t)r * K + k0 + c * 8, &Bs[(rd * 256 + wave * 64) * 8]);
    }
  };

// load k-step S_ fragments into register set SET (row=lane&31, k=s*16+half*8+e
// -> chunk c=s*2+half; LDS slot cp = c ^ (row&7)).
#define G1_LOAD(SET, S_)                                                     \
  { const int c = (S_) * 2 + half;                                           \
    _Pragma("unroll") for (int i = 0; i < 4; ++i) {                          \
      const int ar = wm * 128 + i * 32 + r31;                                \
      const int cp = c ^ (ar & 7);                                           \
      aF[SET][i] = __builtin_bit_cast(f16x8, *(const short8*)&As[ar * 64 + cp * 8]); \
      const int br = wn * 128 + i * 32 + r31;                                \
      const int cq = c ^ (br & 7);                                           \
      bF[SET][i] = __builtin_bit_cast(f16x8, *(const short8*)&Bs[br * 64 + cq * 8]); \
    } }
#define G1_MMA(SET)                                                          \
  _Pragma("unroll") for (int i = 0; i < 4; ++i)                              \
    _Pragma("unroll") for (int j = 0; j < 4; ++j)                            \
      acc[i][j] = __builtin_amdgcn_mfma_f32_32x32x16_f16(aF[SET][i], bF[SET][j], acc[i][j], 0, 0, 0);

  constexpr int NT = K / 64;  // 16
  stage(0, 0);
  asm volatile("s_waitcnt vmcnt(0)" ::: "memory");
  BARRIER;

  for (int t = 0; t < NT; ++t) {
    const unsigned short* As = S + (t & 1) * 16384;
    const unsigned short* Bs = S + 32768 + (t & 1) * 16384;
    if (t + 1 < NT) stage((t + 1) & 1, (t + 1) * 64);  // async; drained at tile end
    f16x8 aF[2][4], bF[2][4];
    G1_LOAD(0, 0)
    G1_LOAD(1, 1)
    G1_MMA(0)        // s=0
    G1_LOAD(0, 2)
    G1_MMA(1)        // s=1
    G1_LOAD(1, 3)
    G1_MMA(0)        // s=2
    G1_MMA(1)        // s=3
    asm volatile("s_waitcnt vmcnt(0)" ::: "memory");
    BARRIER;
  }
#undef G1_LOAD
#undef G1_MMA

  // C/D 32x32 layout: col = lane&31, row = (reg&3)+8*(reg>>2)+4*(lane>>5)
#pragma unroll
  for (int j = 0; j < 4; ++j) {
    const int col = col0 + wn * 128 + j * 32 + r31;
    const float sc = scale[col];
    const float bs = bias[col];
#pragma unroll
    for (int i = 0; i < 4; ++i) {
      const int rbase = row0 + wm * 128 + i * 32 + 4 * half;
#pragma unroll
      for (int r = 0; r < 16; ++r) {
        const int row = rbase + (r & 3) + 8 * (r >> 2);
        float v = fminf(fmaxf(acc[i][j][r] * sc + bs, -1.0f), 1.0f);
        Hout[(size_t)row * HDIM + col] = (signed char)(int)rintf(v * 127.0f);
      }
    }
  }
}

// ---------------- GEMM2 (i8 MFMA, 256x256 tile, 4 waves @ 128x128) ---------
// A: h1_i8 [M][4096], B: state2_i8 [4096][4096] (exact ternary). BK=128 B.
// Same geometry/schedule as gemm1; mfma_i32_32x32x32_i8 exact i32 accum;
// fused OUT_DIM=1 head epilogue.

__global__ __launch_bounds__(256, 1)
void gemm2_kernel(const signed char* __restrict__ A,
                  const signed char* __restrict__ B,
                  const float* __restrict__ scale,   // softplus/127
                  const float* __restrict__ bias,
                  const float* __restrict__ w_out,
                  float* __restrict__ out) {
  constexpr int K = HDIM;
  extern __shared__ __align__(16) char smem[];
  signed char* const S = (signed char*)smem;  // As[2]: 0,32768  Bs[2]: 65536,98304 (bytes)

  const int tid = threadIdx.x;
  const int wave = tid >> 6;
  const int lane = tid & 63;
  const int r31 = lane & 31;
  const int half = lane >> 5;
  const int wm = wave >> 1;
  const int wn = wave & 1;
  const int row0 = blockIdx.y * 256;
  const int col0 = blockIdx.x * 256;

  i32x16 acc[4][4];
#pragma unroll
  for (int i = 0; i < 4; ++i)
#pragma unroll
    for (int j = 0; j < 4; ++j)
#pragma unroll
      for (int r = 0; r < 16; ++r) acc[i][j][r] = 0;

  const signed char* Ab = A + (size_t)row0 * K;
  const signed char* Bb = B + (size_t)col0 * K;

  auto stage = [&](int buf, int k0) {
    signed char* As = S + buf * 32768;
    signed char* Bs = S + 65536 + buf * 32768;
#pragma unroll
    for (int rd = 0; rd < 8; ++rd) {
      const int p = rd * 256 + tid;
      const int r = p >> 3;
      const int c = (p & 7) ^ (r & 7);
      async_copy16(Ab + (size_t)r * K + k0 + c * 16, &As[(rd * 256 + wave * 64) * 16]);
    }
#pragma unroll
    for (int rd = 0; rd < 8; ++rd) {
      const int p = rd * 256 + tid;
      const int r = p >> 3;
      const int c = (p & 7) ^ (r & 7);
      async_copy16(Bb + (size_t)r * K + k0 + c * 16, &Bs[(rd * 256 + wave * 64) * 16]);
    }
  };

// k-step S_: row = lane&31, k = s*32 + half*16 + e -> chunk c = s*2+half
#define G2_LOAD(SET, S_)                                                     \
  { const int c = (S_) * 2 + half;                                           \
    _Pragma("unroll") for (int i = 0; i < 4; ++i) {                          \
      const int ar = wm * 128 + i * 32 + r31;                                \
      const int cp = c ^ (ar & 7);                                           \
      aF[SET][i] = *(const i32x4*)&As[ar * 128 + cp * 16];                   \
      const int br = wn * 128 + i * 32 + r31;                                \
      const int cq = c ^ (br & 7);                                           \
      bF[SET][i] = *(const i32x4*)&Bs[br * 128 + cq * 16];                   \
    } }
#define G2_MMA(SET)                                                          \
  _Pragma("unroll") for (int i = 0; i < 4; ++i)                              \
    _Pragma("unroll") for (int j = 0; j < 4; ++j)                            \
      acc[i][j] = __builtin_amdgcn_mfma_i32_32x32x32_i8(aF[SET][i], bF[SET][j], acc[i][j], 0, 0, 0);

  constexpr int NT = K / 128;  // 32
  stage(0, 0);
  asm volatile("s_waitcnt vmcnt(0)" ::: "memory");
  BARRIER;

  for (int t = 0; t < NT; ++t) {
    const signed char* As = S + (t & 1) * 32768;
    const signed char* Bs = S + 65536 + (t & 1) * 32768;
    if (t + 1 < NT) stage((t + 1) & 1, (t + 1) * 128);
    i32x4 aF[2][4], bF[2][4];
    G2_LOAD(0, 0)
    G2_LOAD(1, 1)
    G2_MMA(0)
    G2_LOAD(0, 2)
    G2_MMA(1)
    G2_LOAD(1, 3)
    G2_MMA(0)
    G2_MMA(1)
    asm volatile("s_waitcnt vmcnt(0)" ::: "memory");
    BARRIER;
  }
#undef G2_LOAD
#undef G2_MMA

  // Fused head: out[row] += sum_col clip(acc*sc+bs)*w_out[col]
#pragma unroll
  for (int i = 0; i < 4; ++i) {
    float rs[16];
#pragma unroll
    for (int r = 0; r < 16; ++r) rs[r] = 0.0f;
#pragma unroll
    for (int j = 0; j < 4; ++j) {
      const int col = col0 + wn * 128 + j * 32 + r31;
      const float sc = scale[col];
      const float bs = bias[col];
      const float w = w_out[col];
#pragma unroll
      for (int r = 0; r < 16; ++r) {
        float v = fminf(fmaxf((float)acc[i][j][r] * sc + bs, -1.0f), 1.0f);
        rs[r] += v * w;
      }
    }
#pragma unroll
    for (int off = 1; off < 32; off <<= 1)
#pragma unroll
      for (int r = 0; r < 16; ++r)
        rs[r] += __shfl_xor(rs[r], off, 64);
    if (r31 == 0) {
      const int rbase = row0 + wm * 128 + i * 32 + 4 * half;
#pragma unroll
      for (int r = 0; r < 16; ++r)
        atomicAdd(&out[rbase + (r & 3) + 8 * (r >> 2)], rs[r]);
    }
  }
}

// ---------------- launch ----------------

extern "C" void kernel_launch(void* const* d_in, const int* in_sizes, int n_in,
                              void* d_out, int out_size, void* d_ws, size_t ws_size,
                              hipStream_t stream) {
  (void)in_sizes; (void)n_in; (void)ws_size;
  const float* x          = (const float*)d_in[0];
  const int*   state1     = (const int*)d_in[1];
  const float* log_scale1 = (const float*)d_in[2];
  const float* bias1      = (const float*)d_in[3];
  const int*   state2     = (const int*)d_in[4];
  const float* log_scale2 = (const float*)d_in[5];
  const float* bias2      = (const float*)d_in[6];
  const float* w_out      = (const float*)d_in[7];
  const float* b_out      = (const float*)d_in[8];
  float* out = (float*)d_out;

  // One-time: both GEMMs need 128 KB dynamic LDS (> default 64 KB cap).
  static int lds_attr_done = 0;
  if (!lds_attr_done) {
    hipFuncSetAttribute((const void*)gemm1_kernel,
                        hipFuncAttributeMaxDynamicSharedMemorySize, 131072);
    hipFuncSetAttribute((const void*)gemm2_kernel,
                        hipFuncAttributeMaxDynamicSharedMemorySize, 131072);
    lds_attr_done = 1;
  }

  char* ws = (char*)d_ws;
  unsigned short* xh  = (unsigned short*)ws; ws += (size_t)BATCH * IN_DIM * 2;  // 32 MB
  unsigned short* s1h = (unsigned short*)ws; ws += (size_t)HDIM * IN_DIM * 2;   // 8 MB
  signed char*    s2q = (signed char*)ws;    ws += (size_t)HDIM * HDIM;         // 16 MB
  signed char*    h1q = (signed char*)ws;    ws += (size_t)BATCH * HDIM;        // 64 MB
  float* scale1 = (float*)ws; ws += HDIM * sizeof(float);
  float* scale2 = (float*)ws; ws += HDIM * sizeof(float);

  const int nx4 = BATCH * IN_DIM / 4;
  const int n1_4 = HDIM * IN_DIM / 4;
  const int n2_4 = HDIM * HDIM / 4;

  cvt_x_f16_kernel<<<(nx4 + 255) / 256, 256, 0, stream>>>(x, xh, nx4);
  cvt_s_kernel<<<(n1_4 + n2_4 + 255) / 256, 256, 0, stream>>>(
      state1, s1h, n1_4, state2, (unsigned int*)s2q, n2_4);
  const int init_n = (out_size > 2 * HDIM) ? out_size : 2 * HDIM;
  scales_init_kernel<<<(init_n + 255) / 256, 256, 0, stream>>>(
      log_scale1, scale1, log_scale2, scale2, b_out, out, out_size);

  dim3 grid(HDIM / 256, BATCH / 256);  // 16 x 64
  gemm1_kernel<<<grid, 256, 131072, stream>>>(xh, s1h, scale1, bias1, h1q);
  gemm2_kernel<<<grid, 256, 131072, stream>>>(h1q, s2q, scale2, bias2, w_out, out);
}

// Round 4
// 538.990 us; speedup vs baseline: 1.1378x; 1.0215x over previous
//
#include <hip/hip_runtime.h>
#include <stdint.h>

#define BATCH 16384
#define IN_DIM 1024
#define HDIM 4096

typedef _Float16 f16x8 __attribute__((ext_vector_type(8)));
typedef short short8 __attribute__((ext_vector_type(8)));
typedef float f32x16 __attribute__((ext_vector_type(16)));
typedef int i32x4 __attribute__((ext_vector_type(4)));
typedef int i32x16 __attribute__((ext_vector_type(16)));

typedef const __attribute__((address_space(1))) void* gas_ptr;
typedef __attribute__((address_space(3))) void* las_ptr;

__device__ __forceinline__ void async_copy16(const void* g, void* l) {
  __builtin_amdgcn_global_load_lds((gas_ptr)g, (las_ptr)l, 16, 0, 0);
}

#define FENCE asm volatile("" ::: "memory")
#define BARRIER do { FENCE; __builtin_amdgcn_s_barrier(); FENCE; } while (0)
// Counted wait + scheduler pin (rule #18: hipcc hoists register-only MFMA past
// inline-asm waits unless a sched_barrier(0) follows).
#define WAIT_LGKM(N) do { asm volatile("s_waitcnt lgkmcnt(" #N ")" ::: "memory"); \
                          __builtin_amdgcn_sched_barrier(0); } while (0)

// ---------------- prep kernels (unchanged) ----------------

__global__ void cvt_x_f16_kernel(const float* __restrict__ in,
                                 unsigned short* __restrict__ out, int n4) {
  int i = blockIdx.x * blockDim.x + threadIdx.x;
  if (i < n4) {
    const float4 v = ((const float4*)in)[i];
    ushort4 o;
    o.x = __builtin_bit_cast(unsigned short, (_Float16)v.x);
    o.y = __builtin_bit_cast(unsigned short, (_Float16)v.y);
    o.z = __builtin_bit_cast(unsigned short, (_Float16)v.z);
    o.w = __builtin_bit_cast(unsigned short, (_Float16)v.w);
    ((ushort4*)out)[i] = o;
  }
}

__global__ void cvt_s_kernel(const int* __restrict__ s1, unsigned short* __restrict__ o1, int n1_4,
                             const int* __restrict__ s2, unsigned int* __restrict__ o2, int n2_4) {
  int i = blockIdx.x * blockDim.x + threadIdx.x;
  if (i < n1_4) {
    const int4 v = ((const int4*)s1)[i];
    ushort4 o;
    o.x = __builtin_bit_cast(unsigned short, (_Float16)(float)v.x);
    o.y = __builtin_bit_cast(unsigned short, (_Float16)(float)v.y);
    o.z = __builtin_bit_cast(unsigned short, (_Float16)(float)v.z);
    o.w = __builtin_bit_cast(unsigned short, (_Float16)(float)v.w);
    ((ushort4*)o1)[i] = o;
  } else if (i < n1_4 + n2_4) {
    const int j = i - n1_4;
    const int4 v = ((const int4*)s2)[j];
    o2[j] = (v.x & 0xffu) | ((v.y & 0xffu) << 8) | ((v.z & 0xffu) << 16) | ((v.w & 0xffu) << 24);
  }
}

// scale1 = max(softplus(ls1),1e-4); scale2 = max(softplus(ls2),1e-4)/127
// out[i] = b_out[0] for ALL out_size rows (launch covers max(out_size, 2*HDIM)).
__global__ void scales_init_kernel(const float* __restrict__ ls1, float* __restrict__ s1,
                                   const float* __restrict__ ls2, float* __restrict__ s2,
                                   const float* __restrict__ b_out, float* __restrict__ out,
                                   int out_n) {
  int i = blockIdx.x * blockDim.x + threadIdx.x;
  if (i < out_n) out[i] = b_out[0];
  if (i < HDIM) {
    float l = ls1[i];
    float sp = (l > 20.0f) ? l : log1pf(expf(l));
    s1[i] = fmaxf(sp, 1e-4f);
  } else if (i < 2 * HDIM) {
    float l = ls2[i - HDIM];
    float sp = (l > 20.0f) ? l : log1pf(expf(l));
    s2[i - HDIM] = fmaxf(sp, 1e-4f) * (1.0f / 127.0f);
  }
}

// ---------------- GEMM1 (f16 MFMA, 256x256 tile, 4 waves @ 128x128) --------
// A: x_f16 [M][1024], B: state1_f16 [4096][1024] (B^T). BK=64 halfs.
// r4 CHANGE: forced in-wave pipe overlap. r3 measured fully-serial LDS+MFMA
// (5300 cyc/tile = 2340 MFMA + 2560 LDS + ovh). With 1 wave/SIMD the only
// overlap source is issue-level pipelining: issue next set's ds_reads, wait
// COUNTED lgkmcnt(8) (current set only), then issue the MFMA cluster while
// the next set's reads drain in the background. Hand-pinned with asm waits
// + sched_barrier(0) (m218 mechanism; rule #18). Staging split A/B halves,
// issued mid-tile between MMA clusters.

__global__ __launch_bounds__(256, 1)
void gemm1_kernel(const unsigned short* __restrict__ A,
                  const unsigned short* __restrict__ B,
                  const float* __restrict__ scale,
                  const float* __restrict__ bias,
                  signed char* __restrict__ Hout) {
  constexpr int K = IN_DIM;
  extern __shared__ __align__(16) char smem[];
  unsigned short* const S = (unsigned short*)smem;  // As[2]: 0,16384  Bs[2]: 32768,49152 (halfs)

  const int tid = threadIdx.x;
  const int wave = tid >> 6;
  const int lane = tid & 63;
  const int r31 = lane & 31;
  const int half = lane >> 5;
  const int wm = wave >> 1;   // 0..1 -> 128 rows
  const int wn = wave & 1;    // 0..1 -> 128 cols
  const int row0 = blockIdx.y * 256;
  const int col0 = blockIdx.x * 256;

  f32x16 acc[4][4];
#pragma unroll
  for (int i = 0; i < 4; ++i)
#pragma unroll
    for (int j = 0; j < 4; ++j)
#pragma unroll
      for (int r = 0; r < 16; ++r) acc[i][j][r] = 0.0f;

  const unsigned short* Ab = A + (size_t)row0 * K;
  const unsigned short* Bb = B + (size_t)col0 * K;

  // A-half / B-half staging: 8 rounds of 256 threads x 16 B each.
  auto stageA = [&](int buf, int k0) {
    unsigned short* As = S + buf * 16384;
#pragma unroll
    for (int rd = 0; rd < 8; ++rd) {
      const int p = rd * 256 + tid;
      const int r = p >> 3;
      const int c = (p & 7) ^ (r & 7);
      async_copy16(Ab + (size_t)r * K + k0 + c * 8, &As[(rd * 256 + wave * 64) * 8]);
    }
  };
  auto stageB = [&](int buf, int k0) {
    unsigned short* Bs = S + 32768 + buf * 16384;
#pragma unroll
    for (int rd = 0; rd < 8; ++rd) {
      const int p = rd * 256 + tid;
      const int r = p >> 3;
      const int c = (p & 7) ^ (r & 7);
      async_copy16(Bb + (size_t)r * K + k0 + c * 8, &Bs[(rd * 256 + wave * 64) * 8]);
    }
  };

// load k-step S_ fragments into register set SET (row=lane&31, k=s*16+half*8+e
// -> chunk c=s*2+half; LDS slot cp = c ^ (row&7)).
#define G1_LOAD(SET, S_)                                                     \
  { const int c = (S_) * 2 + half;                                           \
    _Pragma("unroll") for (int i = 0; i < 4; ++i) {                          \
      const int ar = wm * 128 + i * 32 + r31;                                \
      const int cp = c ^ (ar & 7);                                           \
      aF[SET][i] = __builtin_bit_cast(f16x8, *(const short8*)&As[ar * 64 + cp * 8]); \
      const int br = wn * 128 + i * 32 + r31;                                \
      const int cq = c ^ (br & 7);                                           \
      bF[SET][i] = __builtin_bit_cast(f16x8, *(const short8*)&Bs[br * 64 + cq * 8]); \
    } }
#define G1_MMA(SET)                                                          \
  _Pragma("unroll") for (int i = 0; i < 4; ++i)                              \
    _Pragma("unroll") for (int j = 0; j < 4; ++j)                            \
      acc[i][j] = __builtin_amdgcn_mfma_f32_32x32x16_f16(aF[SET][i], bF[SET][j], acc[i][j], 0, 0, 0);

  constexpr int NT = K / 64;  // 16
  stageA(0, 0);
  stageB(0, 0);
  asm volatile("s_waitcnt vmcnt(0)" ::: "memory");
  BARRIER;

  for (int t = 0; t < NT; ++t) {
    const unsigned short* As = S + (t & 1) * 16384;
    const unsigned short* Bs = S + 32768 + (t & 1) * 16384;
    const int nb = (t + 1) & 1;
    const int nk0 = (t + 1) * 64;
    const bool pf = (t + 1 < NT);
    f16x8 aF[2][4], bF[2][4];

    G1_LOAD(0, 0)          // 8 ds_read (set0)
    FENCE;
    G1_LOAD(1, 1)          // 8 ds_read (set1) -- stays outstanding during MMA(0)
    WAIT_LGKM(8);          // set0 complete; set1 in flight
    G1_MMA(0)
    if (pf) stageA(nb, nk0);   // 8 gload_lds (vmcnt), overlap with MMA
    G1_LOAD(0, 2)          // set2 reads, outstanding during MMA(1)
    WAIT_LGKM(8);          // set1 complete
    G1_MMA(1)
    if (pf) stageB(nb, nk0);
    G1_LOAD(1, 3)          // set3 reads, outstanding during MMA(0)#2
    WAIT_LGKM(8);          // set2 complete
    G1_MMA(0)
    WAIT_LGKM(0);          // set3 complete
    G1_MMA(1)
    asm volatile("s_waitcnt vmcnt(0)" ::: "memory");  // next buffer staged
    BARRIER;
  }
#undef G1_LOAD
#undef G1_MMA

  // C/D 32x32 layout: col = lane&31, row = (reg&3)+8*(reg>>2)+4*(lane>>5)
#pragma unroll
  for (int j = 0; j < 4; ++j) {
    const int col = col0 + wn * 128 + j * 32 + r31;
    const float sc = scale[col];
    const float bs = bias[col];
#pragma unroll
    for (int i = 0; i < 4; ++i) {
      const int rbase = row0 + wm * 128 + i * 32 + 4 * half;
#pragma unroll
      for (int r = 0; r < 16; ++r) {
        const int row = rbase + (r & 3) + 8 * (r >> 2);
        float v = fminf(fmaxf(acc[i][j][r] * sc + bs, -1.0f), 1.0f);
        Hout[(size_t)row * HDIM + col] = (signed char)(int)rintf(v * 127.0f);
      }
    }
  }
}

// ---------------- GEMM2 (i8 MFMA, 256x256 tile, 4 waves @ 128x128) ---------
// A: h1_i8 [M][4096], B: state2_i8 [4096][4096] (exact ternary). BK=128 B.
// Same forced-interleave schedule as gemm1; mfma_i32_32x32x32_i8 exact i32
// accumulation; fused OUT_DIM=1 head epilogue.

__global__ __launch_bounds__(256, 1)
void gemm2_kernel(const signed char* __restrict__ A,
                  const signed char* __restrict__ B,
                  const float* __restrict__ scale,   // softplus/127
                  const float* __restrict__ bias,
                  const float* __restrict__ w_out,
                  float* __restrict__ out) {
  constexpr int K = HDIM;
  extern __shared__ __align__(16) char smem[];
  signed char* const S = (signed char*)smem;  // As[2]: 0,32768  Bs[2]: 65536,98304 (bytes)

  const int tid = threadIdx.x;
  const int wave = tid >> 6;
  const int lane = tid & 63;
  const int r31 = lane & 31;
  const int half = lane >> 5;
  const int wm = wave >> 1;
  const int wn = wave & 1;
  const int row0 = blockIdx.y * 256;
  const int col0 = blockIdx.x * 256;

  i32x16 acc[4][4];
#pragma unroll
  for (int i = 0; i < 4; ++i)
#pragma unroll
    for (int j = 0; j < 4; ++j)
#pragma unroll
      for (int r = 0; r < 16; ++r) acc[i][j][r] = 0;

  const signed char* Ab = A + (size_t)row0 * K;
  const signed char* Bb = B + (size_t)col0 * K;

  auto stageA = [&](int buf, int k0) {
    signed char* As = S + buf * 32768;
#pragma unroll
    for (int rd = 0; rd < 8; ++rd) {
      const int p = rd * 256 + tid;
      const int r = p >> 3;
      const int c = (p & 7) ^ (r & 7);
      async_copy16(Ab + (size_t)r * K + k0 + c * 16, &As[(rd * 256 + wave * 64) * 16]);
    }
  };
  auto stageB = [&](int buf, int k0) {
    signed char* Bs = S + 65536 + buf * 32768;
#pragma unroll
    for (int rd = 0; rd < 8; ++rd) {
      const int p = rd * 256 + tid;
      const int r = p >> 3;
      const int c = (p & 7) ^ (r & 7);
      async_copy16(Bb + (size_t)r * K + k0 + c * 16, &Bs[(rd * 256 + wave * 64) * 16]);
    }
  };

// k-step S_: row = lane&31, k = s*32 + half*16 + e -> chunk c = s*2+half
#define G2_LOAD(SET, S_)                                                     \
  { const int c = (S_) * 2 + half;                                           \
    _Pragma("unroll") for (int i = 0; i < 4; ++i) {                          \
      const int ar = wm * 128 + i * 32 + r31;                                \
      const int cp = c ^ (ar & 7);                                           \
      aF[SET][i] = *(const i32x4*)&As[ar * 128 + cp * 16];                   \
      const int br = wn * 128 + i * 32 + r31;                                \
      const int cq = c ^ (br & 7);                                           \
      bF[SET][i] = *(const i32x4*)&Bs[br * 128 + cq * 16];                   \
    } }
#define G2_MMA(SET)                                                          \
  _Pragma("unroll") for (int i = 0; i < 4; ++i)                              \
    _Pragma("unroll") for (int j = 0; j < 4; ++j)                            \
      acc[i][j] = __builtin_amdgcn_mfma_i32_32x32x32_i8(aF[SET][i], bF[SET][j], acc[i][j], 0, 0, 0);

  constexpr int NT = K / 128;  // 32
  stageA(0, 0);
  stageB(0, 0);
  asm volatile("s_waitcnt vmcnt(0)" ::: "memory");
  BARRIER;

  for (int t = 0; t < NT; ++t) {
    const signed char* As = S + (t & 1) * 32768;
    const signed char* Bs = S + 65536 + (t & 1) * 32768;
    const int nb = (t + 1) & 1;
    const int nk0 = (t + 1) * 128;
    const bool pf = (t + 1 < NT);
    i32x4 aF[2][4], bF[2][4];

    G2_LOAD(0, 0)
    FENCE;
    G2_LOAD(1, 1)
    WAIT_LGKM(8);
    G2_MMA(0)
    if (pf) stageA(nb, nk0);
    G2_LOAD(0, 2)
    WAIT_LGKM(8);
    G2_MMA(1)
    if (pf) stageB(nb, nk0);
    G2_LOAD(1, 3)
    WAIT_LGKM(8);
    G2_MMA(0)
    WAIT_LGKM(0);
    G2_MMA(1)
    asm volatile("s_waitcnt vmcnt(0)" ::: "memory");
    BARRIER;
  }
#undef G2_LOAD
#undef G2_MMA

  // Fused head: out[row] += sum_col clip(acc*sc+bs)*w_out[col]
#pragma unroll
  for (int i = 0; i < 4; ++i) {
    float rs[16];
#pragma unroll
    for (int r = 0; r < 16; ++r) rs[r] = 0.0f;
#pragma unroll
    for (int j = 0; j < 4; ++j) {
      const int col = col0 + wn * 128 + j * 32 + r31;
      const float sc = scale[col];
      const float bs = bias[col];
      const float w = w_out[col];
#pragma unroll
      for (int r = 0; r < 16; ++r) {
        float v = fminf(fmaxf((float)acc[i][j][r] * sc + bs, -1.0f), 1.0f);
        rs[r] += v * w;
      }
    }
#pragma unroll
    for (int off = 1; off < 32; off <<= 1)
#pragma unroll
      for (int r = 0; r < 16; ++r)
        rs[r] += __shfl_xor(rs[r], off, 64);
    if (r31 == 0) {
      const int rbase = row0 + wm * 128 + i * 32 + 4 * half;
#pragma unroll
      for (int r = 0; r < 16; ++r)
        atomicAdd(&out[rbase + (r & 3) + 8 * (r >> 2)], rs[r]);
    }
  }
}

// ---------------- launch ----------------

extern "C" void kernel_launch(void* const* d_in, const int* in_sizes, int n_in,
                              void* d_out, int out_size, void* d_ws, size_t ws_size,
                              hipStream_t stream) {
  (void)in_sizes; (void)n_in; (void)ws_size;
  const float* x          = (const float*)d_in[0];
  const int*   state1     = (const int*)d_in[1];
  const float* log_scale1 = (const float*)d_in[2];
  const float* bias1      = (const float*)d_in[3];
  const int*   state2     = (const int*)d_in[4];
  const float* log_scale2 = (const float*)d_in[5];
  const float* bias2      = (const float*)d_in[6];
  const float* w_out      = (const float*)d_in[7];
  const float* b_out      = (const float*)d_in[8];
  float* out = (float*)d_out;

  // One-time: both GEMMs need 128 KB dynamic LDS (> default 64 KB cap).
  static int lds_attr_done = 0;
  if (!lds_attr_done) {
    hipFuncSetAttribute((const void*)gemm1_kernel,
                        hipFuncAttributeMaxDynamicSharedMemorySize, 131072);
    hipFuncSetAttribute((const void*)gemm2_kernel,
                        hipFuncAttributeMaxDynamicSharedMemorySize, 131072);
    lds_attr_done = 1;
  }

  char* ws = (char*)d_ws;
  unsigned short* xh  = (unsigned short*)ws; ws += (size_t)BATCH * IN_DIM * 2;  // 32 MB
  unsigned short* s1h = (unsigned short*)ws; ws += (size_t)HDIM * IN_DIM * 2;   // 8 MB
  signed char*    s2q = (signed char*)ws;    ws += (size_t)HDIM * HDIM;         // 16 MB
  signed char*    h1q = (signed char*)ws;    ws += (size_t)BATCH * HDIM;        // 64 MB
  float* scale1 = (float*)ws; ws += HDIM * sizeof(float);
  float* scale2 = (float*)ws; ws += HDIM * sizeof(float);

  const int nx4 = BATCH * IN_DIM / 4;
  const int n1_4 = HDIM * IN_DIM / 4;
  const int n2_4 = HDIM * HDIM / 4;

  cvt_x_f16_kernel<<<(nx4 + 255) / 256, 256, 0, stream>>>(x, xh, nx4);
  cvt_s_kernel<<<(n1_4 + n2_4 + 255) / 256, 256, 0, stream>>>(
      state1, s1h, n1_4, state2, (unsigned int*)s2q, n2_4);
  const int init_n = (out_size > 2 * HDIM) ? out_size : 2 * HDIM;
  scales_init_kernel<<<(init_n + 255) / 256, 256, 0, stream>>>(
      log_scale1, scale1, log_scale2, scale2, b_out, out, out_size);

  dim3 grid(HDIM / 256, BATCH / 256);  // 16 x 64
  gemm1_kernel<<<grid, 256, 131072, stream>>>(xh, s1h, scale1, bias1, h1q);
  gemm2_kernel<<<grid, 256, 131072, stream>>>(h1q, s2q, scale2, bias2, w_out, out);
}